// Round 5
// baseline (269.427 us; speedup 1.0000x reference)
//
#include <hip/hip_runtime.h>
#include <hip/hip_bf16.h>
#include <math.h>

// Problem constants
#define B_ 32
#define T_ 4096
#define D_ 256
#define H_ 64
#define A_ 259
#define K_ 256
#define M_ 1024
#define P_ 16
#define STEP_ 273   // idx[i] = 273*i exactly (4095/15)

typedef __attribute__((ext_vector_type(8))) short bf16x8;
typedef __attribute__((ext_vector_type(4))) float f32x4;

__device__ __forceinline__ short f32_to_bf16_rne(float f) {
    unsigned u = __builtin_bit_cast(unsigned, f);
    unsigned r = (u + 0x7fffu + ((u >> 16) & 1u)) >> 16;
    return (short)r;
}

// ---------------------------------------------------------------------------
// K1 (MFMA): sal[b,t] = sigmoid(relu(x@W1+b1)@W2 + b2).
// 1024 blocks x 128 rows (2 row-groups of 64). W1 staged once per block into
// LDS in B-fragment order. Per row-group, ALL 16 x-loads (dwordx4) are hoisted
// into registers before conversion so the compiler can stagger vmcnt waits
// (~16KB in flight per wave) instead of draining per K-step.
// ---------------------------------------------------------------------------
__global__ __launch_bounds__(256, 4) void k1_sal(
    const float* __restrict__ x, const float* __restrict__ W1,
    const float* __restrict__ b1, const float* __restrict__ W2,
    const float* __restrict__ b2, float* __restrict__ sal)
{
    // w1f[kt][nt][lane] = 8 bf16: B[k=kt*32+(lane>>4)*8+j][n=nt*16+(lane&15)]
    __shared__ short w1f[8][4][64 * 8];      // 32 KB
    const int tid = threadIdx.x;

    #pragma unroll
    for (int i = 0; i < 8; ++i) {
        const int e = tid + i * 256;         // 0..2047
        const int lane = e & 63;
        const int ktnt = e >> 6;             // 0..31
        const int kt = ktnt >> 2, nt = ktnt & 3;
        const int n  = nt * 16 + (lane & 15);
        const int k0 = kt * 32 + (lane >> 4) * 8;
        bf16x8 v;
        #pragma unroll
        for (int j = 0; j < 8; ++j)
            v[j] = f32_to_bf16_rne(W1[(size_t)(k0 + j) * H_ + n]);
        *(bf16x8*)&w1f[kt][nt][lane * 8] = v;
    }
    __syncthreads();

    const int wave = tid >> 6, lane = tid & 63;
    const int m = lane & 15, q = lane >> 4;
    const int row0 = blockIdx.x * 128;

    #pragma unroll 1
    for (int g = 0; g < 2; ++g) {
        const int rowbase = row0 + g * 64 + wave * 16;
        const float* xrow = x + (size_t)(rowbase + m) * D_ + q * 8;

        // Hoist all 16 loads for this row-group (64 VGPRs of x in flight).
        float4 xb[16];
        #pragma unroll
        for (int kt = 0; kt < 8; ++kt) {
            xb[2 * kt]     = *(const float4*)(xrow + kt * 32);
            xb[2 * kt + 1] = *(const float4*)(xrow + kt * 32 + 4);
        }

        f32x4 acc[4] = {{0,0,0,0},{0,0,0,0},{0,0,0,0},{0,0,0,0}};
        #pragma unroll
        for (int kt = 0; kt < 8; ++kt) {
            const float4 p0 = xb[2 * kt], p1 = xb[2 * kt + 1];
            bf16x8 a;
            a[0] = f32_to_bf16_rne(p0.x); a[1] = f32_to_bf16_rne(p0.y);
            a[2] = f32_to_bf16_rne(p0.z); a[3] = f32_to_bf16_rne(p0.w);
            a[4] = f32_to_bf16_rne(p1.x); a[5] = f32_to_bf16_rne(p1.y);
            a[6] = f32_to_bf16_rne(p1.z); a[7] = f32_to_bf16_rne(p1.w);
            #pragma unroll
            for (int nt = 0; nt < 4; ++nt) {
                const bf16x8 bfr = *(const bf16x8*)&w1f[kt][nt][lane * 8];
                acc[nt] = __builtin_amdgcn_mfma_f32_16x16x32_bf16(a, bfr, acc[nt], 0, 0, 0);
            }
        }

        // Epilogue: lane holds cols n=nt*16+m, rows q*4+reg (C/D layout).
        float part[4];
        #pragma unroll
        for (int reg = 0; reg < 4; ++reg) {
            float s = 0.f;
            #pragma unroll
            for (int nt = 0; nt < 4; ++nt) {
                const int n = nt * 16 + m;
                const float hv = acc[nt][reg] + b1[n];
                s = fmaf(fmaxf(hv, 0.f), W2[n], s);
            }
            part[reg] = s;
        }
        #pragma unroll
        for (int off = 1; off < 16; off <<= 1) {
            #pragma unroll
            for (int reg = 0; reg < 4; ++reg)
                part[reg] += __shfl_xor(part[reg], off, 64);
        }
        const int r3 = m & 3;
        const float myv = (r3 == 0) ? part[0] : (r3 == 1) ? part[1]
                        : (r3 == 2) ? part[2] : part[3];
        if (m < 4) {
            const float score = myv + b2[0];
            sal[rowbase + q * 4 + m] = 1.f / (1.f + __expf(-score));
        }
    }
}

// ---------------------------------------------------------------------------
// K2: one block per (b, i) pair: directly sums sal[b][0..273*i] (coalesced
// strided loads + shuffle/LDS reduction, no scan barriers). The same grid
// (512x256 = B*T threads) writes y_star with one coalesced store per thread.
// ---------------------------------------------------------------------------
__global__ __launch_bounds__(256) void k2_scan(
    const float* __restrict__ sal, float* __restrict__ cumsel,
    float* __restrict__ ystar)
{
    const int tid = threadIdx.x;

    // y_star: flat mapping, one dword store per thread
    {
        const int g = blockIdx.x * 256 + tid;
        const int ty = g & (T_ - 1);
        ystar[g] = ((ty % STEP_) == 0) ? 1.f : 0.f;
    }

    // prefix sum at position 273*i (inclusive)
    const int b = blockIdx.x >> 4, i = blockIdx.x & 15;
    const int len = STEP_ * i + 1;
    const float* sp = sal + (size_t)b * T_;
    float s = 0.f;
    for (int t = tid; t < len; t += 256) s += sp[t];

    #pragma unroll
    for (int off = 32; off > 0; off >>= 1) s += __shfl_xor(s, off, 64);
    __shared__ float red[4];
    if ((tid & 63) == 0) red[tid >> 6] = s;
    __syncthreads();
    if (tid == 0)
        cumsel[b * P_ + i] = (red[0] + red[1] + red[2] + red[3]) * (1.0f / (float)T_);
}

// ---------------------------------------------------------------------------
// K3a: lifted = tanh(z @ Wl + bl) for the 512 selected rows. 4 rows/block.
// ---------------------------------------------------------------------------
__global__ __launch_bounds__(256) void k3a_lift(
    const float* __restrict__ x, const float* __restrict__ sal,
    const float* __restrict__ cumsel, const float* __restrict__ Wl,
    const float* __restrict__ bl, const float* __restrict__ mu,
    const float* __restrict__ sigma, float* __restrict__ lift)
{
    __shared__ float z[4][260];
    __shared__ float part[4 * 4 * 256];      // [wave][row][k], 16 KB
    const int tid = threadIdx.x;
    const int wave = tid >> 6, lane = tid & 63;

    // ---- Phase 1: wave r owns selected row r ----
    {
        const int r = wave;
        const int s = blockIdx.x * 4 + r;
        const int b = s >> 4, i = s & 15;
        const int pos = STEP_ * i;
        const float* xrow = x + ((size_t)b * T_ + pos) * D_;
        const float4 xv = *(const float4*)(xrow + 4 * lane);
        const float sv = sal[b * T_ + pos];
        const float tn = (float)pos * (1.0f / (float)T_);
        const float cv = cumsel[b * P_ + i];

        float p = xv.x*xv.x + xv.y*xv.y + xv.z*xv.z + xv.w*xv.w;
        #pragma unroll
        for (int off = 32; off > 0; off >>= 1) p += __shfl_xor(p, off, 64);
        const float ss = p + sv * sv + tn * tn + cv * cv;
        const float inv = 1.0f / (sqrtf(ss) + 1e-6f);

        const float4 muv = *(const float4*)(mu + 4 * lane);
        const float4 sgv = *(const float4*)(sigma + 4 * lane);
        z[r][4*lane+0] = (xv.x * inv - muv.x) / sgv.x;
        z[r][4*lane+1] = (xv.y * inv - muv.y) / sgv.y;
        z[r][4*lane+2] = (xv.z * inv - muv.z) / sgv.z;
        z[r][4*lane+3] = (xv.w * inv - muv.w) / sgv.w;
        if (lane < 3) {
            const float e = (lane == 0) ? sv : (lane == 1) ? tn : cv;
            z[r][256 + lane] = (e * inv - mu[256 + lane]) / sigma[256 + lane];
        }
    }
    __syncthreads();

    // ---- Phase 2: wave-split a-loop ----
    const int a0 = wave * 65;
    const int a1 = (wave == 3) ? A_ : a0 + 65;
    f32x4 acc[4] = {{0,0,0,0},{0,0,0,0},{0,0,0,0},{0,0,0,0}};
    const float4* Wl4 = (const float4*)Wl;   // row stride 64 float4

    #pragma unroll 4
    for (int a = a0; a < a1; ++a) {
        const float4 wv = Wl4[a * 64 + lane];
        #pragma unroll
        for (int r = 0; r < 4; ++r) {
            const float zv = z[r][a];        // LDS broadcast
            acc[r][0] = fmaf(zv, wv.x, acc[r][0]);
            acc[r][1] = fmaf(zv, wv.y, acc[r][1]);
            acc[r][2] = fmaf(zv, wv.z, acc[r][2]);
            acc[r][3] = fmaf(zv, wv.w, acc[r][3]);
        }
    }
    {
        f32x4* p4 = (f32x4*)part;
        #pragma unroll
        for (int r = 0; r < 4; ++r)
            p4[(wave * 4 + r) * 64 + lane] = acc[r];
    }
    __syncthreads();

    // ---- Phase 3: reduce + tanh + store ----
    const int r = tid >> 6;                  // 0..3
    const size_t base = (size_t)blockIdx.x * 4 * K_;
    #pragma unroll
    for (int j = 0; j < 4; ++j) {
        const int k = lane + 64 * j;
        float val = bl[k];
        #pragma unroll
        for (int w = 0; w < 4; ++w)
            val += part[(w * 4 + r) * 256 + k];
        lift[base + r * K_ + k] = tanhf(val);
    }
}

// ---------------------------------------------------------------------------
// K3b: tokens = lifted @ Wp + bp. Block = (b, rowhalf of 8, mtile of 256).
// ---------------------------------------------------------------------------
__global__ __launch_bounds__(256) void k3b_tok(
    const float* __restrict__ lift, const float* __restrict__ Wp,
    const float* __restrict__ bp, float* __restrict__ tokens)
{
    __shared__ float ls[8 * K_];             // 8 KB
    __shared__ float part[4 * 8 * 256];      // [wave][row][m], 32 KB
    const int tid = threadIdx.x;
    const int wave = tid >> 6, lane = tid & 63;
    const int mt = blockIdx.x & 3;
    const int rh = (blockIdx.x >> 2) & 1;
    const int b  = blockIdx.x >> 3;
    const int s0 = b * P_ + rh * 8;
    const int m0 = mt * 256;

    const float4* lg = (const float4*)(lift + (size_t)s0 * K_);
    float4* lsl = (float4*)ls;
    lsl[tid] = lg[tid];
    lsl[tid + 256] = lg[tid + 256];
    __syncthreads();

    f32x4 acc[8] = {{0,0,0,0},{0,0,0,0},{0,0,0,0},{0,0,0,0},
                    {0,0,0,0},{0,0,0,0},{0,0,0,0},{0,0,0,0}};
    const float4* Wp4 = (const float4*)(Wp + m0);   // row stride 256 float4

    #pragma unroll 2
    for (int c4 = 0; c4 < 16; ++c4) {
        const int c = wave * 64 + c4 * 4;
        float4 lsv[8];
        #pragma unroll
        for (int r = 0; r < 8; ++r)
            lsv[r] = *(const float4*)&ls[r * K_ + c];   // ds_read_b128 bcast
        #pragma unroll
        for (int cc = 0; cc < 4; ++cc) {
            const float4 wv = Wp4[(size_t)(c + cc) * 256 + lane];
            #pragma unroll
            for (int r = 0; r < 8; ++r) {
                const float lv = (cc == 0) ? lsv[r].x : (cc == 1) ? lsv[r].y
                               : (cc == 2) ? lsv[r].z : lsv[r].w;
                acc[r][0] = fmaf(lv, wv.x, acc[r][0]);
                acc[r][1] = fmaf(lv, wv.y, acc[r][1]);
                acc[r][2] = fmaf(lv, wv.z, acc[r][2]);
                acc[r][3] = fmaf(lv, wv.w, acc[r][3]);
            }
        }
    }
    {
        f32x4* p4 = (f32x4*)part;
        #pragma unroll
        for (int r = 0; r < 8; ++r)
            p4[(wave * 8 + r) * 64 + lane] = acc[r];
    }
    __syncthreads();

    const float bv = bp[m0 + tid];
    #pragma unroll
    for (int r = 0; r < 8; ++r) {
        float val = bv;
        #pragma unroll
        for (int w = 0; w < 4; ++w)
            val += part[(w * 8 + r) * 256 + tid];
        tokens[(size_t)(s0 + r) * M_ + m0 + tid] = val;
    }
}

// ---------------------------------------------------------------------------
extern "C" void kernel_launch(void* const* d_in, const int* in_sizes, int n_in,
                              void* d_out, int out_size, void* d_ws, size_t ws_size,
                              hipStream_t stream)
{
    (void)in_sizes; (void)n_in; (void)out_size; (void)ws_size;
    const float* x  = (const float*)d_in[0];
    const float* W1 = (const float*)d_in[1];
    const float* b1 = (const float*)d_in[2];
    const float* W2 = (const float*)d_in[3];
    const float* b2 = (const float*)d_in[4];
    const float* Wl = (const float*)d_in[5];
    const float* bl = (const float*)d_in[6];
    const float* mu = (const float*)d_in[7];
    const float* sg = (const float*)d_in[8];
    const float* Wp = (const float*)d_in[9];
    const float* bp = (const float*)d_in[10];

    float* out    = (float*)d_out;
    float* tokens = out;                        // B*P*M = 524288 floats
    float* ystar  = out + (size_t)B_ * P_ * M_; // B*T  = 131072 floats

    float* ws     = (float*)d_ws;
    float* sal    = ws;                         // 131072 floats
    float* cumsel = ws + (size_t)B_ * T_;       // 512 floats
    float* lift   = cumsel + B_ * P_;           // 131072 floats

    k1_sal<<<dim3((B_ * T_) / 128), dim3(256), 0, stream>>>(x, W1, b1, W2, b2, sal);
    k2_scan<<<dim3(B_ * P_), dim3(256), 0, stream>>>(sal, cumsel, ystar);
    k3a_lift<<<dim3((B_ * P_) / 4), dim3(256), 0, stream>>>(x, sal, cumsel, Wl, bl, mu, sg, lift);
    k3b_tok<<<dim3(B_ * 2 * 4), dim3(256), 0, stream>>>(lift, Wp, bp, tokens);
}

// Round 6
// 256.852 us; speedup vs baseline: 1.0490x; 1.0490x over previous
//
#include <hip/hip_runtime.h>
#include <hip/hip_bf16.h>
#include <math.h>

// Problem constants
#define B_ 32
#define T_ 4096
#define D_ 256
#define H_ 64
#define A_ 259
#define K_ 256
#define M_ 1024
#define P_ 16
#define STEP_ 273   // idx[i] = 273*i exactly (4095/15)

#define XSTRIDE 260 // padded LDS row stride (floats): 16B-aligned, 2-way banks

typedef __attribute__((ext_vector_type(8))) short bf16x8;
typedef __attribute__((ext_vector_type(4))) float f32x4;

__device__ __forceinline__ short f32_to_bf16_rne(float f) {
    unsigned u = __builtin_bit_cast(unsigned, f);
    unsigned r = (u + 0x7fffu + ((u >> 16) & 1u)) >> 16;
    return (short)r;
}

// ---------------------------------------------------------------------------
// K1 (MFMA + global_load_lds): sal = sigmoid(relu(x@W1+b1)@W2 + b2).
// Grid 512 x 256 threads; block owns 256 rows = 4 tiles of 64. Each wave
// stages ITS OWN 16 rows of x direct-to-LDS (16 x 1KB in flight, no VGPR
// cost) and computes only those rows -> no __syncthreads in the loop.
// W1 lives as B-fragments in VGPRs (gathered once per block from L2).
// 2 blocks/CU (65KB LDS) -> 8 waves/CU x 16KB outstanding = BW-saturating.
// ---------------------------------------------------------------------------
__global__ __launch_bounds__(256, 2) void k1_sal(
    const float* __restrict__ x, const float* __restrict__ W1,
    const float* __restrict__ b1, const float* __restrict__ W2,
    const float* __restrict__ b2, float* __restrict__ sal)
{
    __shared__ float xt[64 * XSTRIDE];       // 66,560 B
    const int tid = threadIdx.x;
    const int wave = tid >> 6, lane = tid & 63;
    const int m = lane & 15, q = lane >> 4;

    // ---- B-fragments for all (kt,nt): frag[j] = W1[kt*32+q*8+j][nt*16+m] ----
    bf16x8 bfr[8][4];                        // 128 VGPRs
    #pragma unroll
    for (int kt = 0; kt < 8; ++kt) {
        #pragma unroll
        for (int nt = 0; nt < 4; ++nt) {
            const int n  = nt * 16 + m;
            const int k0 = kt * 32 + q * 8;
            bf16x8 v;
            #pragma unroll
            for (int j = 0; j < 8; ++j)
                v[j] = f32_to_bf16_rne(W1[(k0 + j) * H_ + n]);
            bfr[kt][nt] = v;
        }
    }
    // epilogue constants (per-lane n = nt*16+m)
    float b1v[4], w2v[4];
    #pragma unroll
    for (int nt = 0; nt < 4; ++nt) {
        b1v[nt] = b1[nt * 16 + m];
        w2v[nt] = W2[nt * 16 + m];
    }
    const float b2s = b2[0];

    const int row0 = blockIdx.x * 256;
    const int rl = wave * 16;                // this wave's first local row

    #pragma unroll 1
    for (int t = 0; t < 4; ++t) {
        const int tilebase = row0 + t * 64;

        // ---- stage own 16 rows: 16 x (64 lanes x 16B) = 16 KB in flight ----
        #pragma unroll
        for (int j = 0; j < 16; ++j) {
            const float* gsrc = x + (size_t)(tilebase + rl + j) * D_ + lane * 4;
            __builtin_amdgcn_global_load_lds(
                (const __attribute__((address_space(1))) unsigned int*)gsrc,
                (__attribute__((address_space(3))) unsigned int*)&xt[(rl + j) * XSTRIDE],
                16, 0, 0);
        }
        __asm__ volatile("s_waitcnt vmcnt(0)" ::: "memory");

        // ---- compute: 8 K-steps x 4 N-tiles of 16x16x32 MFMA ----
        f32x4 acc[4] = {{0,0,0,0},{0,0,0,0},{0,0,0,0},{0,0,0,0}};
        const int abase = (rl + m) * XSTRIDE + q * 8;
        #pragma unroll
        for (int kt = 0; kt < 8; ++kt) {
            const float4 p0 = *(const float4*)&xt[abase + kt * 32];
            const float4 p1 = *(const float4*)&xt[abase + kt * 32 + 4];
            bf16x8 a;
            a[0] = f32_to_bf16_rne(p0.x); a[1] = f32_to_bf16_rne(p0.y);
            a[2] = f32_to_bf16_rne(p0.z); a[3] = f32_to_bf16_rne(p0.w);
            a[4] = f32_to_bf16_rne(p1.x); a[5] = f32_to_bf16_rne(p1.y);
            a[6] = f32_to_bf16_rne(p1.z); a[7] = f32_to_bf16_rne(p1.w);
            #pragma unroll
            for (int nt = 0; nt < 4; ++nt)
                acc[nt] = __builtin_amdgcn_mfma_f32_16x16x32_bf16(a, bfr[kt][nt], acc[nt], 0, 0, 0);
        }

        // ---- epilogue: relu + W2-dot; C/D layout col=m, row=q*4+reg ----
        float part[4];
        #pragma unroll
        for (int reg = 0; reg < 4; ++reg) {
            float s = 0.f;
            #pragma unroll
            for (int nt = 0; nt < 4; ++nt) {
                const float hv = acc[nt][reg] + b1v[nt];
                s = fmaf(fmaxf(hv, 0.f), w2v[nt], s);
            }
            part[reg] = s;
        }
        #pragma unroll
        for (int off = 1; off < 16; off <<= 1) {
            #pragma unroll
            for (int reg = 0; reg < 4; ++reg)
                part[reg] += __shfl_xor(part[reg], off, 64);
        }
        const int r3 = m & 3;
        const float myv = (r3 == 0) ? part[0] : (r3 == 1) ? part[1]
                        : (r3 == 2) ? part[2] : part[3];
        if (m < 4) {
            const float score = myv + b2s;
            sal[tilebase + rl + q * 4 + m] = 1.f / (1.f + __expf(-score));
        }
    }
}

// ---------------------------------------------------------------------------
// K2: one block per (b, i): sums sal[b][0..273*i] directly; same grid writes
// y_star with one coalesced store per thread.
// ---------------------------------------------------------------------------
__global__ __launch_bounds__(256) void k2_scan(
    const float* __restrict__ sal, float* __restrict__ cumsel,
    float* __restrict__ ystar)
{
    const int tid = threadIdx.x;

    {
        const int g = blockIdx.x * 256 + tid;
        const int ty = g & (T_ - 1);
        ystar[g] = ((ty % STEP_) == 0) ? 1.f : 0.f;
    }

    const int b = blockIdx.x >> 4, i = blockIdx.x & 15;
    const int len = STEP_ * i + 1;
    const float* sp = sal + (size_t)b * T_;
    float s = 0.f;
    for (int t = tid; t < len; t += 256) s += sp[t];

    #pragma unroll
    for (int off = 32; off > 0; off >>= 1) s += __shfl_xor(s, off, 64);
    __shared__ float red[4];
    if ((tid & 63) == 0) red[tid >> 6] = s;
    __syncthreads();
    if (tid == 0)
        cumsel[b * P_ + i] = (red[0] + red[1] + red[2] + red[3]) * (1.0f / (float)T_);
}

// ---------------------------------------------------------------------------
// K3a: lifted = tanh(z @ Wl + bl) for the 512 selected rows. 4 rows/block.
// ---------------------------------------------------------------------------
__global__ __launch_bounds__(256) void k3a_lift(
    const float* __restrict__ x, const float* __restrict__ sal,
    const float* __restrict__ cumsel, const float* __restrict__ Wl,
    const float* __restrict__ bl, const float* __restrict__ mu,
    const float* __restrict__ sigma, float* __restrict__ lift)
{
    __shared__ float z[4][260];
    __shared__ float part[4 * 4 * 256];      // [wave][row][k], 16 KB
    const int tid = threadIdx.x;
    const int wave = tid >> 6, lane = tid & 63;

    // ---- Phase 1: wave r owns selected row r ----
    {
        const int r = wave;
        const int s = blockIdx.x * 4 + r;
        const int b = s >> 4, i = s & 15;
        const int pos = STEP_ * i;
        const float* xrow = x + ((size_t)b * T_ + pos) * D_;
        const float4 xv = *(const float4*)(xrow + 4 * lane);
        const float sv = sal[b * T_ + pos];
        const float tn = (float)pos * (1.0f / (float)T_);
        const float cv = cumsel[b * P_ + i];

        float p = xv.x*xv.x + xv.y*xv.y + xv.z*xv.z + xv.w*xv.w;
        #pragma unroll
        for (int off = 32; off > 0; off >>= 1) p += __shfl_xor(p, off, 64);
        const float ss = p + sv * sv + tn * tn + cv * cv;
        const float inv = 1.0f / (sqrtf(ss) + 1e-6f);

        const float4 muv = *(const float4*)(mu + 4 * lane);
        const float4 sgv = *(const float4*)(sigma + 4 * lane);
        z[r][4*lane+0] = (xv.x * inv - muv.x) / sgv.x;
        z[r][4*lane+1] = (xv.y * inv - muv.y) / sgv.y;
        z[r][4*lane+2] = (xv.z * inv - muv.z) / sgv.z;
        z[r][4*lane+3] = (xv.w * inv - muv.w) / sgv.w;
        if (lane < 3) {
            const float e = (lane == 0) ? sv : (lane == 1) ? tn : cv;
            z[r][256 + lane] = (e * inv - mu[256 + lane]) / sigma[256 + lane];
        }
    }
    __syncthreads();

    // ---- Phase 2: wave-split a-loop ----
    const int a0 = wave * 65;
    const int a1 = (wave == 3) ? A_ : a0 + 65;
    f32x4 acc[4] = {{0,0,0,0},{0,0,0,0},{0,0,0,0},{0,0,0,0}};
    const float4* Wl4 = (const float4*)Wl;   // row stride 64 float4

    #pragma unroll 4
    for (int a = a0; a < a1; ++a) {
        const float4 wv = Wl4[a * 64 + lane];
        #pragma unroll
        for (int r = 0; r < 4; ++r) {
            const float zv = z[r][a];        // LDS broadcast
            acc[r][0] = fmaf(zv, wv.x, acc[r][0]);
            acc[r][1] = fmaf(zv, wv.y, acc[r][1]);
            acc[r][2] = fmaf(zv, wv.z, acc[r][2]);
            acc[r][3] = fmaf(zv, wv.w, acc[r][3]);
        }
    }
    {
        f32x4* p4 = (f32x4*)part;
        #pragma unroll
        for (int r = 0; r < 4; ++r)
            p4[(wave * 4 + r) * 64 + lane] = acc[r];
    }
    __syncthreads();

    // ---- Phase 3: reduce + tanh + store ----
    const int r = tid >> 6;                  // 0..3
    const size_t base = (size_t)blockIdx.x * 4 * K_;
    #pragma unroll
    for (int j = 0; j < 4; ++j) {
        const int k = lane + 64 * j;
        float val = bl[k];
        #pragma unroll
        for (int w = 0; w < 4; ++w)
            val += part[(w * 4 + r) * 256 + k];
        lift[base + r * K_ + k] = tanhf(val);
    }
}

// ---------------------------------------------------------------------------
// K3b: tokens = lifted @ Wp + bp. Block = (b, rowhalf of 8, mtile of 256).
// ---------------------------------------------------------------------------
__global__ __launch_bounds__(256) void k3b_tok(
    const float* __restrict__ lift, const float* __restrict__ Wp,
    const float* __restrict__ bp, float* __restrict__ tokens)
{
    __shared__ float ls[8 * K_];             // 8 KB
    __shared__ float part[4 * 8 * 256];      // [wave][row][m], 32 KB
    const int tid = threadIdx.x;
    const int wave = tid >> 6, lane = tid & 63;
    const int mt = blockIdx.x & 3;
    const int rh = (blockIdx.x >> 2) & 1;
    const int b  = blockIdx.x >> 3;
    const int s0 = b * P_ + rh * 8;
    const int m0 = mt * 256;

    const float4* lg = (const float4*)(lift + (size_t)s0 * K_);
    float4* lsl = (float4*)ls;
    lsl[tid] = lg[tid];
    lsl[tid + 256] = lg[tid + 256];
    __syncthreads();

    f32x4 acc[8] = {{0,0,0,0},{0,0,0,0},{0,0,0,0},{0,0,0,0},
                    {0,0,0,0},{0,0,0,0},{0,0,0,0},{0,0,0,0}};
    const float4* Wp4 = (const float4*)(Wp + m0);   // row stride 256 float4

    #pragma unroll 2
    for (int c4 = 0; c4 < 16; ++c4) {
        const int c = wave * 64 + c4 * 4;
        float4 lsv[8];
        #pragma unroll
        for (int r = 0; r < 8; ++r)
            lsv[r] = *(const float4*)&ls[r * K_ + c];   // ds_read_b128 bcast
        #pragma unroll
        for (int cc = 0; cc < 4; ++cc) {
            const float4 wv = Wp4[(size_t)(c + cc) * 256 + lane];
            #pragma unroll
            for (int r = 0; r < 8; ++r) {
                const float lv = (cc == 0) ? lsv[r].x : (cc == 1) ? lsv[r].y
                               : (cc == 2) ? lsv[r].z : lsv[r].w;
                acc[r][0] = fmaf(lv, wv.x, acc[r][0]);
                acc[r][1] = fmaf(lv, wv.y, acc[r][1]);
                acc[r][2] = fmaf(lv, wv.z, acc[r][2]);
                acc[r][3] = fmaf(lv, wv.w, acc[r][3]);
            }
        }
    }
    {
        f32x4* p4 = (f32x4*)part;
        #pragma unroll
        for (int r = 0; r < 8; ++r)
            p4[(wave * 8 + r) * 64 + lane] = acc[r];
    }
    __syncthreads();

    const float bv = bp[m0 + tid];
    #pragma unroll
    for (int r = 0; r < 8; ++r) {
        float val = bv;
        #pragma unroll
        for (int w = 0; w < 4; ++w)
            val += part[(w * 8 + r) * 256 + tid];
        tokens[(size_t)(s0 + r) * M_ + m0 + tid] = val;
    }
}

// ---------------------------------------------------------------------------
extern "C" void kernel_launch(void* const* d_in, const int* in_sizes, int n_in,
                              void* d_out, int out_size, void* d_ws, size_t ws_size,
                              hipStream_t stream)
{
    (void)in_sizes; (void)n_in; (void)out_size; (void)ws_size;
    const float* x  = (const float*)d_in[0];
    const float* W1 = (const float*)d_in[1];
    const float* b1 = (const float*)d_in[2];
    const float* W2 = (const float*)d_in[3];
    const float* b2 = (const float*)d_in[4];
    const float* Wl = (const float*)d_in[5];
    const float* bl = (const float*)d_in[6];
    const float* mu = (const float*)d_in[7];
    const float* sg = (const float*)d_in[8];
    const float* Wp = (const float*)d_in[9];
    const float* bp = (const float*)d_in[10];

    float* out    = (float*)d_out;
    float* tokens = out;                        // B*P*M = 524288 floats
    float* ystar  = out + (size_t)B_ * P_ * M_; // B*T  = 131072 floats

    float* ws     = (float*)d_ws;
    float* sal    = ws;                         // 131072 floats
    float* cumsel = ws + (size_t)B_ * T_;       // 512 floats
    float* lift   = cumsel + B_ * P_;           // 131072 floats

    k1_sal<<<dim3((B_ * T_) / 256), dim3(256), 0, stream>>>(x, W1, b1, W2, b2, sal);
    k2_scan<<<dim3(B_ * P_), dim3(256), 0, stream>>>(sal, cumsel, ystar);
    k3a_lift<<<dim3((B_ * P_) / 4), dim3(256), 0, stream>>>(x, sal, cumsel, Wl, bl, mu, sg, lift);
    k3b_tok<<<dim3(B_ * 2 * 4), dim3(256), 0, stream>>>(lift, Wp, bp, tokens);
}